// Round 2
// 886.828 us; speedup vs baseline: 1.5730x; 1.5730x over previous
//
#include <hip/hip_runtime.h>

// AxialAttention on MI355X (gfx950).
// Shapes: q,k,v (2,8,512,32,64) fp32. B = 2*8*32 = 512 batches, L = 512, D = 64.
// qf[Bi, l, d] = q[bh*1048576 + l*2048 + d2*64 + d]  where bh = Bi>>5, d2 = Bi&31.
// Outputs: out (16,777,216 f32, same layout as q) then probs (512,512,512 f32).
//
// One workgroup = 4 waves = one (batch, 64-row q-tile). Each wave owns 16 q rows.
// S (16x512 per wave) lives entirely in MFMA C-fragments (32 x f32x4 = 128 VGPRs).
// K and V are staged through double-buffered, XOR-swizzled LDS tiles (64 k-rows)
// with cooperative float4 loads; V is stored transposed so PV B-frags are single
// ds_read_b128s. P transpose goes through per-wave (barrier-free) LDS.

typedef __bf16 b16x8 __attribute__((ext_vector_type(8)));
typedef __bf16 b16x4 __attribute__((ext_vector_type(4)));
typedef float f32x4 __attribute__((ext_vector_type(4)));

#define NEG_INF (-1e9f)

__global__ __launch_bounds__(256, 2)
void axial_attn_kernel(const float* __restrict__ q,
                       const float* __restrict__ k,
                       const float* __restrict__ v,
                       const float* __restrict__ am,
                       const float* __restrict__ hm,
                       float* __restrict__ out,
                       float* __restrict__ probs) {
    const int bid = blockIdx.x;       // 0..4095
    // XCD-aware swizzle (bijective): all 8 q-tiles of a batch land on the same
    // XCD (= bid%8) back-to-back, so K/V re-reads hit that XCD's private L2.
    const int Bi = (bid >> 6) * 8 + (bid & 7);   // batch 0..511
    const int qt = (bid >> 3) & 7;               // q-tile 0..7
    const int bh = Bi >> 5;
    const int d2 = Bi & 31;
    const int tid = threadIdx.x;
    const int w    = tid >> 6;        // wave 0..3
    const int lane = tid & 63;
    const int ln   = lane & 15;
    const int quad = lane >> 4;
    const int q0   = qt * 64 + w * 16;

    const size_t base = (size_t)bh * 1048576 + (size_t)d2 * 64;
    const float* qb = q + base;
    const float* kb = k + base;
    const float* vb = v + base;

    // LDS: K row-major bf16 [64][64], V transposed bf16 [d=64][k=64], both
    // double-buffered + 16B-chunk XOR swizzle (chunk ^= row&7). P per-wave dbuf.
    __shared__ __align__(16) __bf16 kls[2][64][64];    // 16 KB
    __shared__ __align__(16) __bf16 vls[2][64][64];    // 16 KB
    __shared__ __align__(16) __bf16 pls[4][2][16][40]; // 10 KB

    // staging maps
    const int r_k = tid >> 2, c_k = (tid & 3) * 16;        // K: 1 row, 16 cols
    const int r_v = (tid >> 4) * 4, c_v = (tid & 15) * 4;  // V: 4x4 block

    // ---- Q A-fragments: lane holds Q[q0+ln][c*32 + quad*8 + j], j=0..7 (float4 loads)
    b16x8 aq0, aq1;
    {
        const float4* qrow = (const float4*)(qb + (size_t)(q0 + ln) * 2048 + quad * 8);
        float4 f0 = qrow[0], f1 = qrow[1];   // cols quad*8 .. +7
        float4 f2 = qrow[8], f3 = qrow[9];   // cols 32+quad*8 .. +7
        aq0[0] = (__bf16)f0.x; aq0[1] = (__bf16)f0.y; aq0[2] = (__bf16)f0.z; aq0[3] = (__bf16)f0.w;
        aq0[4] = (__bf16)f1.x; aq0[5] = (__bf16)f1.y; aq0[6] = (__bf16)f1.z; aq0[7] = (__bf16)f1.w;
        aq1[0] = (__bf16)f2.x; aq1[1] = (__bf16)f2.y; aq1[2] = (__bf16)f2.z; aq1[3] = (__bf16)f2.w;
        aq1[4] = (__bf16)f3.x; aq1[5] = (__bf16)f3.y; aq1[6] = (__bf16)f3.z; aq1[7] = (__bf16)f3.w;
    }

    // ---- staging helpers
    auto k_load = [&](int kt, float4* reg) {
        const float4* s4 = (const float4*)(kb + (size_t)(kt * 64 + r_k) * 2048 + c_k);
        reg[0] = s4[0]; reg[1] = s4[1]; reg[2] = s4[2]; reg[3] = s4[3];
    };
    auto k_write = [&](int b, const float4* reg) {
        const float* f = (const float*)reg;
        __bf16 h[16];
        #pragma unroll
        for (int i = 0; i < 16; ++i) h[i] = (__bf16)f[i];
        const int ch0 = c_k >> 3;
        const int sw  = r_k & 7;
        *(b16x8*)&kls[b][r_k][((ch0 ^ sw) << 3)]       = *(b16x8*)&h[0];
        *(b16x8*)&kls[b][r_k][(((ch0 + 1) ^ sw) << 3)] = *(b16x8*)&h[8];
    };
    auto v_load = [&](int vt, float4* reg) {
        #pragma unroll
        for (int i = 0; i < 4; ++i)
            reg[i] = *(const float4*)(vb + (size_t)(vt * 64 + r_v + i) * 2048 + c_v);
    };
    auto v_write = [&](int b, const float4* reg) {
        const float* f = (const float*)reg;   // f[i*4+j] = V[r_v+i][c_v+j]
        const int sw0 = r_v >> 3;
        const int off = r_v & 7;              // 0 or 4
        #pragma unroll
        for (int j = 0; j < 4; ++j) {
            const int c = c_v + j;
            b16x4 p;
            p[0] = (__bf16)f[0 * 4 + j];
            p[1] = (__bf16)f[1 * 4 + j];
            p[2] = (__bf16)f[2 * 4 + j];
            p[3] = (__bf16)f[3 * 4 + j];
            *(b16x4*)&vls[b][c][(((sw0 ^ (c & 7)) << 3) | off)] = p;
        }
    };

    // ---- S = Q K^T over 8 double-buffered 64-row K tiles
    f32x4 acc[32];
    #pragma unroll
    for (int t = 0; t < 32; ++t) acc[t] = (f32x4){0.f, 0.f, 0.f, 0.f};

    float4 kreg[4];
    k_load(0, kreg);
    k_write(0, kreg);
    __syncthreads();

    #pragma unroll
    for (int kt = 0; kt < 8; ++kt) {
        if (kt < 7) k_load(kt + 1, kreg);        // issue early (hides under MFMAs)
        #pragma unroll
        for (int tt = 0; tt < 4; ++tt) {
            const int t   = kt * 4 + tt;
            const int row = tt * 16 + ln;
            const int sw  = row & 7;
            b16x8 bk0 = *(const b16x8*)&kls[kt & 1][row][((quad ^ sw) << 3)];
            b16x8 bk1 = *(const b16x8*)&kls[kt & 1][row][(((4 + quad) ^ sw) << 3)];
            acc[t] = __builtin_amdgcn_mfma_f32_16x16x32_bf16(aq0, bk0, acc[t], 0, 0, 0);
            acc[t] = __builtin_amdgcn_mfma_f32_16x16x32_bf16(aq1, bk1, acc[t], 0, 0, 0);
        }
        if (kt < 7) {
            k_write((kt + 1) & 1, kreg);         // write late (vmcnt waited here)
            __syncthreads();
        }
    }

    // ---- issue V tile 0 loads now; softmax VALU work hides their latency
    float4 vreg[4];
    v_load(0, vreg);

    // ---- scale, attention mask, row max
    const int rowbase = q0 + quad * 4;
    const float* amp = am + (size_t)rowbase * 512 + ln;
    const float* hmp = hm + (size_t)rowbase * 512 + ln;

    float mrow[4] = {NEG_INF, NEG_INF, NEG_INF, NEG_INF};
    #pragma unroll
    for (int t = 0; t < 32; ++t) {
        #pragma unroll
        for (int r = 0; r < 4; ++r) {
            float s = acc[t][r] * 0.125f;               // 1/sqrt(64)
            float m = amp[r * 512 + t * 16];
            s = (m == 0.0f) ? NEG_INF : s;
            acc[t][r] = s;
            mrow[r] = fmaxf(mrow[r], s);
        }
    }
    #pragma unroll
    for (int off = 1; off < 16; off <<= 1) {
        #pragma unroll
        for (int r = 0; r < 4; ++r)
            mrow[r] = fmaxf(mrow[r], __shfl_xor(mrow[r], off, 64));
    }

    // ---- exp and row sum
    float srow[4] = {0.f, 0.f, 0.f, 0.f};
    #pragma unroll
    for (int t = 0; t < 32; ++t) {
        #pragma unroll
        for (int r = 0; r < 4; ++r) {
            float e = __expf(acc[t][r] - mrow[r]);
            acc[t][r] = e;
            srow[r] += e;
        }
    }
    #pragma unroll
    for (int off = 1; off < 16; off <<= 1) {
        #pragma unroll
        for (int r = 0; r < 4; ++r)
            srow[r] += __shfl_xor(srow[r], off, 64);
    }
    float inv[4];
    #pragma unroll
    for (int r = 0; r < 4; ++r) inv[r] = 1.0f / srow[r];

    // ---- probs = softmax * head_mask; write to global, keep in acc for PV
    float* pout = probs + (size_t)Bi * 262144 + (size_t)rowbase * 512 + ln;
    #pragma unroll
    for (int t = 0; t < 32; ++t) {
        #pragma unroll
        for (int r = 0; r < 4; ++r) {
            float p = acc[t][r] * inv[r] * hmp[r * 512 + t * 16];
            acc[t][r] = p;
            pout[r * 512 + t * 16] = p;
        }
    }

    // ---- stage V tile 0 (transposed) and run PV over 8 double-buffered tiles
    v_write(0, vreg);
    __syncthreads();

    f32x4 oacc[4];
    #pragma unroll
    for (int n = 0; n < 4; ++n) oacc[n] = (f32x4){0.f, 0.f, 0.f, 0.f};

    #pragma unroll
    for (int vt = 0; vt < 8; ++vt) {
        if (vt < 7) v_load(vt + 1, vreg);        // issue early
        #pragma unroll
        for (int kc = 0; kc < 2; ++kc) {
            const int g  = vt * 2 + kc;          // 32-col P chunk 0..15
            const int pb = g & 1;
            // P (C-layout) -> A-layout through per-wave LDS; same-wave lgkmcnt
            // ordering only, no barrier needed.
            #pragma unroll
            for (int t = 0; t < 2; ++t)
                #pragma unroll
                for (int r = 0; r < 4; ++r)
                    pls[w][pb][quad * 4 + r][t * 16 + ln] = (__bf16)acc[g * 2 + t][r];
            b16x8 pa = *(const b16x8*)&pls[w][pb][ln][quad * 8];
            #pragma unroll
            for (int n = 0; n < 4; ++n) {
                const int vrow = n * 16 + ln;
                b16x8 bv = *(const b16x8*)&vls[vt & 1][vrow]
                               [(((kc * 4 + quad) ^ (vrow & 7)) << 3)];
                oacc[n] = __builtin_amdgcn_mfma_f32_16x16x32_bf16(pa, bv, oacc[n], 0, 0, 0);
            }
        }
        if (vt < 7) {
            v_write((vt + 1) & 1, vreg);         // write late
            __syncthreads();
        }
    }

    // ---- epilogue: out[bh][row][d2][dim], C-frag row=quad*4+r, col=n*16+ln
    float* ob = out + base;
    #pragma unroll
    for (int n = 0; n < 4; ++n)
        #pragma unroll
        for (int r = 0; r < 4; ++r)
            ob[(size_t)(rowbase + r) * 2048 + n * 16 + ln] = oacc[n][r];
}

extern "C" void kernel_launch(void* const* d_in, const int* in_sizes, int n_in,
                              void* d_out, int out_size, void* d_ws, size_t ws_size,
                              hipStream_t stream) {
    const float* q  = (const float*)d_in[0];
    const float* k  = (const float*)d_in[1];
    const float* v  = (const float*)d_in[2];
    const float* am = (const float*)d_in[3];
    const float* hm = (const float*)d_in[4];
    float* out   = (float*)d_out;
    float* probs = out + 16777216;   // out is (2,8,512,32,64); probs is (512,512,512)

    dim3 grid(4096), block(256);
    hipLaunchKernelGGL(axial_attn_kernel, grid, block, 0, stream,
                       q, k, v, am, hm, out, probs);
}